// Round 1
// baseline (451.879 us; speedup 1.0000x reference)
//
#include <hip/hip_runtime.h>
#include <hip/hip_bf16.h>

// Problem constants: B=8, T=256, V=32, D=256
// Per-v GEMM: M=N=2048 (= B*T rows of (i,q)/(j,k)), K=256
// Global layout: feature[B,T,V,D] -> element (row=(i*T+q), d) of slice v at
//   feat[(row*V + v)*D + d], row stride = V*D = 8192 floats.

typedef __attribute__((ext_vector_type(8))) __bf16 bf16x8;
typedef __attribute__((ext_vector_type(4))) float f32x4;

__device__ __forceinline__ unsigned short f2bf(float f) {
    unsigned u = __builtin_bit_cast(unsigned, f);
    u += 0x7FFFu + ((u >> 16) & 1u);   // round-to-nearest-even (no NaNs in data)
    return (unsigned short)(u >> 16);
}

// ws layout (floats): total[2048] | self[2048] | ap[2048]
__global__ __launch_bounds__(256) void infonce_main(
    const float* __restrict__ feat, const float* __restrict__ feat_aug,
    float* __restrict__ total, float* __restrict__ selfp, float* __restrict__ ap)
{
    // 128x128 tile, K=256 in 4 stages of BK=64. Pad rows by +8 bf16 (16B).
    __shared__ __align__(16) unsigned short As[128][72];
    __shared__ __align__(16) unsigned short Bs[128][72];
    __shared__ float ls_row[128];
    __shared__ float ls_col[128];

    const int tid  = threadIdx.x;
    const int lane = tid & 63;
    const int w    = tid >> 6;        // wave 0..3
    const int wm   = w >> 1;          // wave row (0..1) -> 64 rows
    const int wn   = w & 1;           // wave col (0..1) -> 64 cols
    const int lrow = lane & 15;
    const int quad = lane >> 4;

    const int tileM = blockIdx.x & 15;
    const int tileN = blockIdx.x >> 4;
    const int v     = blockIdx.y;
    // diagonal (i==j) iff row-batch == col-batch; 128-row tiles, 256 rows/batch
    const bool diag = (tileM >> 1) == (tileN >> 1);

    if (tid < 128) ls_row[tid] = 0.0f;
    else           ls_col[tid - 128] = 0.0f;

    const float* aBase = feat     + (size_t)v * 256;
    const float* bBase = feat_aug + (size_t)v * 256;

    f32x4 acc[4][4];
    #pragma unroll
    for (int i = 0; i < 4; ++i)
        #pragma unroll
        for (int j = 0; j < 4; ++j)
            acc[i][j] = (f32x4){0.f, 0.f, 0.f, 0.f};

    const int srow = tid >> 4;         // 0..15
    const int scol = (tid & 15) * 4;   // 0..60, float4 granularity

    for (int s = 0; s < 4; ++s) {
        const int k0 = s * 64;
        if (s) __syncthreads();        // previous stage's LDS reads done
        #pragma unroll
        for (int it = 0; it < 8; ++it) {
            const int row = it * 16 + srow;
            const float4 a4 = *(const float4*)(aBase + (size_t)(tileM * 128 + row) * 8192 + k0 + scol);
            const float4 b4 = *(const float4*)(bBase + (size_t)(tileN * 128 + row) * 8192 + k0 + scol);
            uint2 wa, wb;
            wa.x = (unsigned)f2bf(a4.x) | ((unsigned)f2bf(a4.y) << 16);
            wa.y = (unsigned)f2bf(a4.z) | ((unsigned)f2bf(a4.w) << 16);
            wb.x = (unsigned)f2bf(b4.x) | ((unsigned)f2bf(b4.y) << 16);
            wb.y = (unsigned)f2bf(b4.z) | ((unsigned)f2bf(b4.w) << 16);
            *(uint2*)&As[row][scol] = wa;
            *(uint2*)&Bs[row][scol] = wb;
        }
        __syncthreads();
        #pragma unroll
        for (int kk = 0; kk < 64; kk += 32) {
            bf16x8 af[4], bfr[4];
            #pragma unroll
            for (int t = 0; t < 4; ++t) {
                af[t]  = *(const bf16x8*)&As[wm * 64 + t * 16 + lrow][kk + quad * 8];
                bfr[t] = *(const bf16x8*)&Bs[wn * 64 + t * 16 + lrow][kk + quad * 8];
            }
            #pragma unroll
            for (int ti = 0; ti < 4; ++ti)
                #pragma unroll
                for (int tj = 0; tj < 4; ++tj)
                    acc[ti][tj] = __builtin_amdgcn_mfma_f32_16x16x32_bf16(
                        af[ti], bfr[tj], acc[ti][tj], 0, 0, 0);
        }
    }

    // Epilogue: E = exp(score); row sums (all blocks), col sums (diag blocks).
    // C/D layout per 16x16 tile: col = lane&15, row = quad*4 + reg.
    float colp0 = 0.f, colp1 = 0.f, colp2 = 0.f, colp3 = 0.f;
    #pragma unroll
    for (int ti = 0; ti < 4; ++ti) {
        #pragma unroll
        for (int r = 0; r < 4; ++r) {
            float e0 = __expf(acc[ti][0][r]);
            float e1 = __expf(acc[ti][1][r]);
            float e2 = __expf(acc[ti][2][r]);
            float e3 = __expf(acc[ti][3][r]);
            colp0 += e0; colp1 += e1; colp2 += e2; colp3 += e3;
            float rp = (e0 + e1) + (e2 + e3);
            rp += __shfl_xor(rp, 1);
            rp += __shfl_xor(rp, 2);
            rp += __shfl_xor(rp, 4);
            rp += __shfl_xor(rp, 8);
            if (lrow == 0)
                atomicAdd(&ls_row[wm * 64 + ti * 16 + quad * 4 + r], rp);
        }
    }
    if (diag) {
        float cp[4] = {colp0, colp1, colp2, colp3};
        #pragma unroll
        for (int tj = 0; tj < 4; ++tj) {
            float q = cp[tj];
            q += __shfl_xor(q, 16);
            q += __shfl_xor(q, 32);
            if (lane < 16)
                atomicAdd(&ls_col[wn * 64 + tj * 16 + lane], q);
        }
    }
    __syncthreads();
    if (tid < 128) {
        const float rs = ls_row[tid];
        const int rowg = tileM * 128 + tid;       // = i*T + q
        atomicAdd(&total[rowg], rs);
        if (diag) atomicAdd(&selfp[rowg], rs);
    } else if (diag) {
        const int t2 = tid - 128;
        atomicAdd(&ap[tileN * 128 + t2], ls_col[t2]);  // col index = i*T + k on diag
    }
}

__global__ __launch_bounds__(256) void infonce_finalize(
    const float* __restrict__ total, const float* __restrict__ selfp,
    const float* __restrict__ ap, float* __restrict__ out)
{
    __shared__ float red[4];
    const int tid = threadIdx.x;
    float s = 0.f;
    for (int e = tid; e < 2048; e += 256) {
        const float an = total[e] - selfp[e];
        s += logf(an / ap[e]);               // -log(ap/an)
    }
    #pragma unroll
    for (int m = 32; m >= 1; m >>= 1) s += __shfl_xor(s, m);
    if ((tid & 63) == 0) red[tid >> 6] = s;
    __syncthreads();
    if (tid == 0) out[0] = (red[0] + red[1] + red[2] + red[3]) * (1.0f / 256.0f);
}

extern "C" void kernel_launch(void* const* d_in, const int* in_sizes, int n_in,
                              void* d_out, int out_size, void* d_ws, size_t ws_size,
                              hipStream_t stream) {
    const float* feat     = (const float*)d_in[0];
    const float* feat_aug = (const float*)d_in[1];
    float* total = (float*)d_ws;
    float* selfp = total + 2048;
    float* ap    = selfp + 2048;
    hipMemsetAsync(d_ws, 0, 3 * 2048 * sizeof(float), stream);
    infonce_main<<<dim3(256, 32), 256, 0, stream>>>(feat, feat_aug, total, selfp, ap);
    infonce_finalize<<<1, 256, 0, stream>>>(total, selfp, ap, (float*)d_out);
}

// Round 2
// 256.465 us; speedup vs baseline: 1.7620x; 1.7620x over previous
//
#include <hip/hip_runtime.h>
#include <hip/hip_bf16.h>

// Problem: B=8, T=256, V=32, D=256.
// Per-v GEMM: M=N=2048 (rows = i*T+q / j*T+k), K=256, then exp + 3 reductions.
// feature[B,T,V,D]: element (row, v, d) at feat[(row*32 + v)*256 + d].
// Packed layout (workspace): p[v][row][d] bf16, per-v slice contiguous (1 MB).

typedef __attribute__((ext_vector_type(8))) __bf16 bf16x8;
typedef __attribute__((ext_vector_type(4))) float f32x4;

__device__ __forceinline__ unsigned short f2bf(float f) {
    unsigned u = __builtin_bit_cast(unsigned, f);
    u += 0x7FFFu + ((u >> 16) & 1u);   // RNE (no NaNs in data)
    return (unsigned short)(u >> 16);
}

__device__ __forceinline__ void async16(const unsigned short* g, unsigned short* l) {
    __builtin_amdgcn_global_load_lds(
        (const __attribute__((address_space(1))) unsigned int*)g,
        (__attribute__((address_space(3))) unsigned int*)l,
        16, 0, 0);
}

// ---------------- repack: fp32 [row][v][d] -> bf16 [v][row][d] ----------------
__global__ __launch_bounds__(256) void infonce_repack(
    const float* __restrict__ feat, const float* __restrict__ feat_aug,
    unsigned short* __restrict__ pA, unsigned short* __restrict__ pB)
{
    const int row = blockIdx.x;                       // 0..2047
    const int tid = threadIdx.x;
    const float* src = (blockIdx.y == 0 ? feat : feat_aug) + (size_t)row * 8192;
    unsigned short* dst = (blockIdx.y == 0 ? pA : pB);
    #pragma unroll
    for (int it = 0; it < 8; ++it) {
        const int idx = it * 1024 + tid * 4;          // float index in this row
        const int v = idx >> 8;
        const int d = idx & 255;
        const float4 f = *(const float4*)(src + idx); // wave: 1024 B contiguous
        uint2 p;
        p.x = (unsigned)f2bf(f.x) | ((unsigned)f2bf(f.y) << 16);
        p.y = (unsigned)f2bf(f.z) | ((unsigned)f2bf(f.w) << 16);
        *(uint2*)(dst + ((size_t)v * 2048 + row) * 256 + d) = p;  // wave: 512 B contig
    }
}

// ---------------- main: per-v 2048x2048x256 bf16 GEMM + exp + reductions -----
// LDS: unpadded [128 rows][64 bf16] per operand, XOR-swizzled colgroups:
//   physical cg = logical cg ^ (row & 7)   (cg = 16B group, 8 per row)
// global_load_lds: lane l of an 8-row issue -> row +l/8, physical cg l%8,
//   so it fetches logical cg (l%8)^(l/8) from global.
__global__ __launch_bounds__(256) void infonce_main_fast(
    const unsigned short* __restrict__ pA, const unsigned short* __restrict__ pB,
    float* __restrict__ total, float* __restrict__ selfp, float* __restrict__ ap)
{
    __shared__ __align__(16) unsigned short As[128 * 64];
    __shared__ __align__(16) unsigned short Bs[128 * 64];
    __shared__ float ls_row[128];
    __shared__ float ls_col[128];

    const int tid  = threadIdx.x;
    const int lane = tid & 63;
    const int w    = tid >> 6;        // wave 0..3
    const int wm   = w >> 1;
    const int wn   = w & 1;
    const int lrow = lane & 15;
    const int quad = lane >> 4;

    const int tileM = blockIdx.x & 15;
    const int tileN = blockIdx.x >> 4;
    const int v     = blockIdx.y;
    const bool diag = (tileM >> 1) == (tileN >> 1);   // i == j (256-row batches)

    if (tid < 128) ls_row[tid] = 0.f;
    else           ls_col[tid - 128] = 0.f;

    // staging addresses: wave w stages rows [w*32, w*32+32) of both tiles
    const int row8 = lane >> 3;       // 0..7
    const int cg   = (lane & 7) ^ row8;  // logical colgroup this lane fetches
    const unsigned short* aRow =
        pA + ((size_t)v * 2048 + tileM * 128 + w * 32 + row8) * 256 + cg * 8;
    const unsigned short* bRow =
        pB + ((size_t)v * 2048 + tileN * 128 + w * 32 + row8) * 256 + cg * 8;

    f32x4 acc[4][4];
    #pragma unroll
    for (int i = 0; i < 4; ++i)
        #pragma unroll
        for (int j = 0; j < 4; ++j)
            acc[i][j] = (f32x4){0.f, 0.f, 0.f, 0.f};

    const int swz = lrow & 7;

    for (int s = 0; s < 4; ++s) {
        if (s) __syncthreads();
        #pragma unroll
        for (int issue = 0; issue < 4; ++issue) {
            async16(aRow + (size_t)issue * 8 * 256 + s * 64,
                    &As[(w * 32 + issue * 8) * 64]);
            async16(bRow + (size_t)issue * 8 * 256 + s * 64,
                    &Bs[(w * 32 + issue * 8) * 64]);
        }
        __syncthreads();   // compiler drains vmcnt here
        #pragma unroll
        for (int kh = 0; kh < 2; ++kh) {
            bf16x8 af[4], bfr[4];
            #pragma unroll
            for (int t = 0; t < 4; ++t) {
                const int rA = wm * 64 + t * 16 + lrow;
                const int rB = wn * 64 + t * 16 + lrow;
                const int pc = (((kh << 2) + quad) ^ swz) * 8;
                af[t]  = *(const bf16x8*)&As[rA * 64 + pc];
                bfr[t] = *(const bf16x8*)&Bs[rB * 64 + pc];
            }
            #pragma unroll
            for (int ti = 0; ti < 4; ++ti)
                #pragma unroll
                for (int tj = 0; tj < 4; ++tj)
                    acc[ti][tj] = __builtin_amdgcn_mfma_f32_16x16x32_bf16(
                        af[ti], bfr[tj], acc[ti][tj], 0, 0, 0);
        }
    }

    // Epilogue: E = exp(score); row sums (all blocks), col sums (diag blocks).
    // C/D layout per 16x16 tile: col = lane&15, row = quad*4 + reg.
    float colp[4] = {0.f, 0.f, 0.f, 0.f};
    #pragma unroll
    for (int ti = 0; ti < 4; ++ti) {
        #pragma unroll
        for (int r = 0; r < 4; ++r) {
            float e0 = __expf(acc[ti][0][r]);
            float e1 = __expf(acc[ti][1][r]);
            float e2 = __expf(acc[ti][2][r]);
            float e3 = __expf(acc[ti][3][r]);
            colp[0] += e0; colp[1] += e1; colp[2] += e2; colp[3] += e3;
            float rp = (e0 + e1) + (e2 + e3);
            rp += __shfl_xor(rp, 1);
            rp += __shfl_xor(rp, 2);
            rp += __shfl_xor(rp, 4);
            rp += __shfl_xor(rp, 8);
            if (lrow == 0)
                atomicAdd(&ls_row[wm * 64 + ti * 16 + quad * 4 + r], rp);
        }
    }
    if (diag) {
        #pragma unroll
        for (int tj = 0; tj < 4; ++tj) {
            float q = colp[tj];
            q += __shfl_xor(q, 16);
            q += __shfl_xor(q, 32);
            if (lane < 16)
                atomicAdd(&ls_col[wn * 64 + tj * 16 + lane], q);
        }
    }
    __syncthreads();
    if (tid < 128) {
        const float rs = ls_row[tid];
        const int rowg = tileM * 128 + tid;           // = i*T + q
        atomicAdd(&total[rowg], rs);
        if (diag) atomicAdd(&selfp[rowg], rs);
    } else if (diag) {
        const int t2 = tid - 128;
        atomicAdd(&ap[tileN * 128 + t2], ls_col[t2]); // col index = i*T + k on diag
    }
}

// ---------------- fallback main (round-1 kernel, fp32 staging) ---------------
__global__ __launch_bounds__(256) void infonce_main_slow(
    const float* __restrict__ feat, const float* __restrict__ feat_aug,
    float* __restrict__ total, float* __restrict__ selfp, float* __restrict__ ap)
{
    __shared__ __align__(16) unsigned short As[128][72];
    __shared__ __align__(16) unsigned short Bs[128][72];
    __shared__ float ls_row[128];
    __shared__ float ls_col[128];

    const int tid  = threadIdx.x;
    const int lane = tid & 63;
    const int w    = tid >> 6;
    const int wm   = w >> 1;
    const int wn   = w & 1;
    const int lrow = lane & 15;
    const int quad = lane >> 4;

    const int tileM = blockIdx.x & 15;
    const int tileN = blockIdx.x >> 4;
    const int v     = blockIdx.y;
    const bool diag = (tileM >> 1) == (tileN >> 1);

    if (tid < 128) ls_row[tid] = 0.0f;
    else           ls_col[tid - 128] = 0.0f;

    const float* aBase = feat     + (size_t)v * 256;
    const float* bBase = feat_aug + (size_t)v * 256;

    f32x4 acc[4][4];
    #pragma unroll
    for (int i = 0; i < 4; ++i)
        #pragma unroll
        for (int j = 0; j < 4; ++j)
            acc[i][j] = (f32x4){0.f, 0.f, 0.f, 0.f};

    const int srow = tid >> 4;
    const int scol = (tid & 15) * 4;

    for (int s = 0; s < 4; ++s) {
        const int k0 = s * 64;
        if (s) __syncthreads();
        #pragma unroll
        for (int it = 0; it < 8; ++it) {
            const int row = it * 16 + srow;
            const float4 a4 = *(const float4*)(aBase + (size_t)(tileM * 128 + row) * 8192 + k0 + scol);
            const float4 b4 = *(const float4*)(bBase + (size_t)(tileN * 128 + row) * 8192 + k0 + scol);
            uint2 wa, wb;
            wa.x = (unsigned)f2bf(a4.x) | ((unsigned)f2bf(a4.y) << 16);
            wa.y = (unsigned)f2bf(a4.z) | ((unsigned)f2bf(a4.w) << 16);
            wb.x = (unsigned)f2bf(b4.x) | ((unsigned)f2bf(b4.y) << 16);
            wb.y = (unsigned)f2bf(b4.z) | ((unsigned)f2bf(b4.w) << 16);
            *(uint2*)&As[row][scol] = wa;
            *(uint2*)&Bs[row][scol] = wb;
        }
        __syncthreads();
        #pragma unroll
        for (int kk = 0; kk < 64; kk += 32) {
            bf16x8 af[4], bfr[4];
            #pragma unroll
            for (int t = 0; t < 4; ++t) {
                af[t]  = *(const bf16x8*)&As[wm * 64 + t * 16 + lrow][kk + quad * 8];
                bfr[t] = *(const bf16x8*)&Bs[wn * 64 + t * 16 + lrow][kk + quad * 8];
            }
            #pragma unroll
            for (int ti = 0; ti < 4; ++ti)
                #pragma unroll
                for (int tj = 0; tj < 4; ++tj)
                    acc[ti][tj] = __builtin_amdgcn_mfma_f32_16x16x32_bf16(
                        af[ti], bfr[tj], acc[ti][tj], 0, 0, 0);
        }
    }

    float colp[4] = {0.f, 0.f, 0.f, 0.f};
    #pragma unroll
    for (int ti = 0; ti < 4; ++ti) {
        #pragma unroll
        for (int r = 0; r < 4; ++r) {
            float e0 = __expf(acc[ti][0][r]);
            float e1 = __expf(acc[ti][1][r]);
            float e2 = __expf(acc[ti][2][r]);
            float e3 = __expf(acc[ti][3][r]);
            colp[0] += e0; colp[1] += e1; colp[2] += e2; colp[3] += e3;
            float rp = (e0 + e1) + (e2 + e3);
            rp += __shfl_xor(rp, 1);
            rp += __shfl_xor(rp, 2);
            rp += __shfl_xor(rp, 4);
            rp += __shfl_xor(rp, 8);
            if (lrow == 0)
                atomicAdd(&ls_row[wm * 64 + ti * 16 + quad * 4 + r], rp);
        }
    }
    if (diag) {
        #pragma unroll
        for (int tj = 0; tj < 4; ++tj) {
            float q = colp[tj];
            q += __shfl_xor(q, 16);
            q += __shfl_xor(q, 32);
            if (lane < 16)
                atomicAdd(&ls_col[wn * 64 + tj * 16 + lane], q);
        }
    }
    __syncthreads();
    if (tid < 128) {
        const float rs = ls_row[tid];
        const int rowg = tileM * 128 + tid;
        atomicAdd(&total[rowg], rs);
        if (diag) atomicAdd(&selfp[rowg], rs);
    } else if (diag) {
        const int t2 = tid - 128;
        atomicAdd(&ap[tileN * 128 + t2], ls_col[t2]);
    }
}

__global__ __launch_bounds__(256) void infonce_finalize(
    const float* __restrict__ total, const float* __restrict__ selfp,
    const float* __restrict__ ap, float* __restrict__ out)
{
    __shared__ float red[4];
    const int tid = threadIdx.x;
    float s = 0.f;
    for (int e = tid; e < 2048; e += 256) {
        const float an = total[e] - selfp[e];
        s += logf(an / ap[e]);
    }
    #pragma unroll
    for (int m = 32; m >= 1; m >>= 1) s += __shfl_xor(s, m);
    if ((tid & 63) == 0) red[tid >> 6] = s;
    __syncthreads();
    if (tid == 0) out[0] = (red[0] + red[1] + red[2] + red[3]) * (1.0f / 256.0f);
}

extern "C" void kernel_launch(void* const* d_in, const int* in_sizes, int n_in,
                              void* d_out, int out_size, void* d_ws, size_t ws_size,
                              hipStream_t stream) {
    const float* feat     = (const float*)d_in[0];
    const float* feat_aug = (const float*)d_in[1];
    float* total = (float*)d_ws;
    float* selfp = total + 2048;
    float* ap    = selfp + 2048;
    hipMemsetAsync(d_ws, 0, 3 * 2048 * sizeof(float), stream);

    const size_t packElems = (size_t)32 * 2048 * 256;              // per tensor
    const size_t need = 32768 + 2 * packElems * sizeof(unsigned short);
    if (ws_size >= need) {
        unsigned short* pA = (unsigned short*)((char*)d_ws + 32768);
        unsigned short* pB = pA + packElems;
        infonce_repack<<<dim3(2048, 2), 256, 0, stream>>>(feat, feat_aug, pA, pB);
        infonce_main_fast<<<dim3(256, 32), 256, 0, stream>>>(pA, pB, total, selfp, ap);
    } else {
        infonce_main_slow<<<dim3(256, 32), 256, 0, stream>>>(feat, feat_aug, total, selfp, ap);
    }
    infonce_finalize<<<1, 256, 0, stream>>>(total, selfp, ap, (float*)d_out);
}